// Round 9
// baseline (51.391 us; speedup 1.0000x reference)
//
#include <hip/hip_runtime.h>
#include <hip/hip_bf16.h>

#define TWOPI_OVER_B 0.049087385212340517f  // 2*pi/128

typedef __attribute__((ext_vector_type(8))) short bf16x8;
typedef __attribute__((ext_vector_type(4))) float f32x4;

static __device__ __forceinline__ unsigned short f2bf(float f) {
    __hip_bfloat16 h = __float2bfloat16(f);
    return *reinterpret_cast<unsigned short*>(&h);
}
static __device__ __forceinline__ unsigned long long pack4(float a, float b, float c, float d) {
    return (unsigned long long)f2bf(a) | ((unsigned long long)f2bf(b) << 16)
         | ((unsigned long long)f2bf(c) << 32) | ((unsigned long long)f2bf(d) << 48);
}

// ---------------------------------------------------------------------------
// Prep: 16 blocks. Each: local fB via table -> W-spectrum MFMA DFT -> BmatT
// (R4/R5/R7/R8-validated body), plus writes its 1/16 stripe of global
// fragB/fragCi directly from the table.
__global__ __launch_bounds__(256) void k_prep(const float* __restrict__ W,
                                              unsigned short* __restrict__ fragB,
                                              unsigned short* __restrict__ fragCi,
                                              unsigned short* __restrict__ BmatT) {
    __shared__ char smem[73984];               // xs/Yl union
    __shared__ unsigned short fB[18432];
    __shared__ float tbl[256];
    int tid = threadIdx.x;
    int bw = blockIdx.x;                       // 0..15, 2 o's each
    unsigned long long* xs8 = (unsigned long long*)smem;
    float* Yl = (float*)smem;

    if (tid < 128) {
        float s, c;
        sincosf(TWOPI_OVER_B * (float)tid, &s, &c);
        tbl[tid] = c; tbl[128 + tid] = s;
    }
    __syncthreads();

    for (int i = tid; i < 18432; i += 256) {   // local fragB via table
        int e = i & 7, l2 = (i >> 3) & 63, kb = (i >> 9) & 3, c = i >> 11;
        int kr = c * 16 + (l2 & 15);
        int t  = kb * 32 + (l2 >> 4) * 8 + e;
        float v = 0.f;
        if (kr < 65)       v =  tbl[(kr * t) & 127];
        else if (kr < 130) v = -tbl[128 + (((kr - 65) * t) & 127)];
        fB[i] = f2bf(v);
    }
    // global fragB stripe (1152/block) + fragCi stripe (1280/block), from tbl
    for (int i = bw * 1152 + tid; i < (bw + 1) * 1152; i += 256) {
        int e = i & 7, l2 = (i >> 3) & 63, kb = (i >> 9) & 3, c = i >> 11;
        int kr = c * 16 + (l2 & 15);
        int t  = kb * 32 + (l2 >> 4) * 8 + e;
        float v = 0.f;
        if (kr < 65)       v =  tbl[(kr * t) & 127];
        else if (kr < 130) v = -tbl[128 + (((kr - 65) * t) & 127)];
        fragB[i] = f2bf(v);
    }
    for (int i = bw * 1280 + tid; i < (bw + 1) * 1280; i += 256) {
        int e = i & 7, l2 = (i >> 3) & 63;
        int ckb = i >> 9; int kb = ckb % 5, c = ckb / 5;
        int kr = kb * 32 + (l2 >> 4) * 8 + e;
        int t  = c * 16 + (l2 & 15);
        float v = 0.f;
        if (kr < 65)       v =  tbl[(kr * t) & 127];
        else if (kr < 130) v = -tbl[128 + (((kr - 65) * t) & 127)];
        fragCi[i] = f2bf(v);
    }
    #pragma unroll
    for (int it = 0; it < 8; ++it) {           // stage W: 64 rows x 128
        int f  = tid + it * 256;
        float4 wa = ((const float4*)W)[(size_t)bw * 2048 + f];
        int rl = f >> 5;
        int t0 = (f & 31) * 4;
        int byte = (rl * 256 + t0 * 2) ^ ((rl & 7) << 4);
        xs8[byte >> 3] = pack4(wa.x, wa.y, wa.z, wa.w);
    }
    __syncthreads();

    int l = tid & 63, w = tid >> 6;
    int rl_a = w * 16 + (l & 15);
    int coff = (l >> 4) * 16;
    bf16x8 a[4];
    #pragma unroll
    for (int kb = 0; kb < 4; ++kb) {
        int byte = (rl_a * 256 + kb * 64 + coff) ^ ((rl_a & 7) << 4);
        a[kb] = *(const bf16x8*)(smem + byte);
    }
    __syncthreads();                           // xs dead; Yl overwrites

    f32x4 acc[9];
    #pragma unroll
    for (int c = 0; c < 9; ++c) acc[c] = (f32x4)0.f;
    #pragma unroll
    for (int c = 0; c < 9; ++c)
        #pragma unroll
        for (int kb = 0; kb < 4; ++kb)
            acc[c] = __builtin_amdgcn_mfma_f32_16x16x32_bf16(a[kb], ((const bf16x8*)fB)[(c * 4 + kb) * 64 + l], acc[c], 0, 0, 0);

    int rowd = w * 16 + (l >> 4) * 4;
    int cold = l & 15;
    #pragma unroll
    for (int c = 0; c < 9; ++c)
        #pragma unroll
        for (int r = 0; r < 4; ++r)
            Yl[(rowd + r) * 145 + c * 16 + cold] = acc[c][r];
    __syncthreads();

    int o0 = bw * 2;
    for (int c2 = tid; c2 < 4160; c2 += 256) {
        int k = c2 >> 6, sub = c2 & 63;
        int oo = sub >> 5, h = (sub >> 4) & 1, t = sub & 15;
        int j0 = t * 4;
        float sc = (k == 0 || k == 64) ? (1.f / 128.f) : (2.f / 128.f);
        int col; float sgn;
        if (j0 < 32) { col = h ? 65 + k : k;  sgn = h ? -sc : sc; }
        else         { col = h ? k : 65 + k;  sgn = sc; }
        int rlb = oo * 32 + (j0 & 31);
        unsigned long long pk = pack4(sgn * Yl[(rlb + 0) * 145 + col], sgn * Yl[(rlb + 1) * 145 + col],
                                      sgn * Yl[(rlb + 2) * 145 + col], sgn * Yl[(rlb + 3) * 145 + col]);
        int o2 = h * 32 + o0 + oo;
        *(unsigned long long*)(BmatT + ((size_t)k * 64 + o2) * 64 + j0) = pk;
    }
}

// ---------------------------------------------------------------------------
// Stage A: 1024 blocks, 1 n each. Waves: wr=row-half (j 0-15 / 16-31),
// wc=c-half (c 0-4 / 5-8). A-frags loaded direct to registers (no LDS stage).
// Yl f32 [32][145] bounce (R3-proven) -> coalesced Xb[k][n][j2] stores.
__global__ __launch_bounds__(256) void k_fdft(const float* __restrict__ x,
                                              const float* __restrict__ D,
                                              const bf16x8* __restrict__ fragB,
                                              unsigned short* __restrict__ Xb) {
    __shared__ float Yl[32 * 145];             // 18560 B
    int tid = threadIdx.x, l = tid & 63, w = tid >> 6;
    int lr = l & 15, lq = l >> 4;
    int wr = w & 1, wc = w >> 1;
    int n = blockIdx.x;

    int j = wr * 16 + lr;                      // A row = block j index
    const float* xr = x + (size_t)n * 4096 + j * 128 + lq * 8;
    const float* Dr = D + j * 128 + lq * 8;
    union { bf16x8 v; unsigned long long q[2]; } au[4];
    #pragma unroll
    for (int kb = 0; kb < 4; ++kb) {
        float4 x0 = *(const float4*)(xr + kb * 32);
        float4 x1 = *(const float4*)(xr + kb * 32 + 4);
        float4 d0 = *(const float4*)(Dr + kb * 32);
        float4 d1 = *(const float4*)(Dr + kb * 32 + 4);
        au[kb].q[0] = pack4(x0.x * d0.x, x0.y * d0.y, x0.z * d0.z, x0.w * d0.w);
        au[kb].q[1] = pack4(x1.x * d1.x, x1.y * d1.y, x1.z * d1.z, x1.w * d1.w);
    }

    int cbase = wc * 5;                        // wc=0: c 0..4, wc=1: c 5..8
    f32x4 acc[5];
    #pragma unroll
    for (int ci = 0; ci < 5; ++ci) acc[ci] = (f32x4)0.f;
    #pragma unroll
    for (int ci = 0; ci < 5; ++ci) {
        int c = cbase + ci;
        if (c < 9) {
            #pragma unroll
            for (int kb = 0; kb < 4; ++kb)
                acc[ci] = __builtin_amdgcn_mfma_f32_16x16x32_bf16(au[kb].v, fragB[(c * 4 + kb) * 64 + l], acc[ci], 0, 0, 0);
        }
    }

    int rowd = wr * 16 + lq * 4;
    #pragma unroll
    for (int ci = 0; ci < 5; ++ci) {
        int c = cbase + ci;
        if (c < 9) {
            #pragma unroll
            for (int r = 0; r < 4; ++r)
                Yl[(rowd + r) * 145 + c * 16 + lr] = acc[ci][r];
        }
    }
    __syncthreads();

    for (int c2 = tid; c2 < 1040; c2 += 256) { // 65 k x 16 t-items
        int k = c2 >> 4, t = c2 & 15;
        int j0 = t * 4;
        int col = (j0 < 32) ? k : 65 + k;
        int rlb = j0 & 31;
        unsigned long long pk = pack4(Yl[(rlb + 0) * 145 + col], Yl[(rlb + 1) * 145 + col],
                                      Yl[(rlb + 2) * 145 + col], Yl[(rlb + 3) * 145 + col]);
        *(unsigned long long*)(Xb + ((size_t)k * 1024 + n) * 64 + j0) = pk;
    }
}

// ---------------------------------------------------------------------------
// Stage B: 1040 blocks = 65 k x 16 m-tiles (M=64). Wave: 16 rows x 64 cols.
__global__ __launch_bounds__(256) void k_einsum(const unsigned short* __restrict__ Xb,
                                                const unsigned short* __restrict__ BmatT,
                                                unsigned short* __restrict__ Y2) {
    __shared__ char lds[8192];
    int tid = threadIdx.x, l = tid & 63, w = tid >> 6;
    int k = blockIdx.x >> 4, mt = blockIdx.x & 15;
    int m0 = mt * 64 + w * 16;
    int lr = l & 15, lq = l >> 4;

    bf16x8 a[2], b[4][2];
    #pragma unroll
    for (int kb = 0; kb < 2; ++kb)
        a[kb] = *(const bf16x8*)(Xb + ((size_t)k * 1024 + m0 + lr) * 64 + kb * 32 + lq * 8);
    #pragma unroll
    for (int cf = 0; cf < 4; ++cf)
        #pragma unroll
        for (int kb = 0; kb < 2; ++kb)
            b[cf][kb] = *(const bf16x8*)(BmatT + ((size_t)k * 64 + cf * 16 + lr) * 64 + kb * 32 + lq * 8);

    f32x4 acc[4];
    #pragma unroll
    for (int cf = 0; cf < 4; ++cf) acc[cf] = (f32x4)0.f;
    #pragma unroll
    for (int cf = 0; cf < 4; ++cf) {
        acc[cf] = __builtin_amdgcn_mfma_f32_16x16x32_bf16(a[0], b[cf][0], acc[cf], 0, 0, 0);
        acc[cf] = __builtin_amdgcn_mfma_f32_16x16x32_bf16(a[1], b[cf][1], acc[cf], 0, 0, 0);
    }

    #pragma unroll
    for (int cf = 0; cf < 4; ++cf)
        #pragma unroll
        for (int rr = 0; rr < 4; ++rr) {
            int row = lq * 4 + rr;             // 0..15 within wave tile
            int col = cf * 16 + lr;
            int byte = w * 2048 + ((row * 128 + col * 2) ^ ((row & 7) << 4));
            *(unsigned short*)(lds + byte) = f2bf(acc[cf][rr]);
        }
    __syncthreads();
    #pragma unroll
    for (int i = 0; i < 2; ++i) {
        int row = i * 8 + (l >> 3);            // 0..15
        int byte = w * 2048 + ((row * 128 + (l & 7) * 16) ^ ((row & 7) << 4));
        bf16x8 v = *(const bf16x8*)(lds + byte);
        *(bf16x8*)(Y2 + ((size_t)k * 1024 + m0 + row) * 64 + (l & 7) * 8) = v;
    }
}

// ---------------------------------------------------------------------------
// Stage C: 1024 blocks, 1 n each (rows = 32 o). Waves: wr=row-half, wc=c-half.
__global__ __launch_bounds__(256) void k_idft(const unsigned short* __restrict__ Y2,
                                              const bf16x8* __restrict__ fragCi,
                                              float* __restrict__ out) {
    __shared__ char smem[10240];               // ys[32][160] bf16, swizzled
    int tid = threadIdx.x;
    int n = blockIdx.x;

    for (int i = tid; i < 1024; i += 256) {    // zero pad cols [130,160)
        int rl = i >> 5, cc = i & 31;
        if (cc < 30) {
            int byte = (rl * 320 + (130 + cc) * 2) ^ ((rl & 7) << 4);
            *(unsigned short*)(smem + byte) = 0;
        }
    }
    for (int c2 = tid; c2 < 1040; c2 += 256) { // 65 k x 16 t-items
        int k = c2 >> 4, t = c2 & 15;
        unsigned long long v = *(const unsigned long long*)(Y2 + ((size_t)k * 1024 + n) * 64 + t * 4);
        int o2_0 = t * 4;
        int col = (o2_0 < 32) ? k : 65 + k;
        int r0 = o2_0 & 31;
        #pragma unroll
        for (int i = 0; i < 4; ++i) {
            int rl = r0 + i;
            int byte = (rl * 320 + col * 2) ^ ((rl & 7) << 4);
            *(unsigned short*)(smem + byte) = (unsigned short)(v >> (16 * i));
        }
    }
    __syncthreads();

    int l = tid & 63, w = tid >> 6;
    int lr = l & 15, lq = l >> 4;
    int wr = w & 1, wc = w >> 1;
    int rl_a = wr * 16 + lr;
    bf16x8 a[5];
    #pragma unroll
    for (int kb = 0; kb < 5; ++kb) {
        int byte = (rl_a * 320 + kb * 64 + lq * 16) ^ ((rl_a & 7) << 4);
        a[kb] = *(const bf16x8*)(smem + byte);
    }
    int cbase = wc * 4;                        // wc=0: c 0..3, wc=1: c 4..7
    f32x4 acc[4];
    #pragma unroll
    for (int ci = 0; ci < 4; ++ci) acc[ci] = (f32x4)0.f;
    #pragma unroll
    for (int ci = 0; ci < 4; ++ci)
        #pragma unroll
        for (int kb = 0; kb < 5; ++kb)
            acc[ci] = __builtin_amdgcn_mfma_f32_16x16x32_bf16(a[kb], fragCi[((cbase + ci) * 5 + kb) * 64 + l], acc[ci], 0, 0, 0);

    int rowg = n * 32 + wr * 16 + lq * 4;      // out row = n*32 + o
    #pragma unroll
    for (int ci = 0; ci < 4; ++ci)
        #pragma unroll
        for (int r = 0; r < 4; ++r)
            out[(size_t)(rowg + r) * 128 + (cbase + ci) * 16 + lr] = acc[ci][r];
}

// ---------------------------------------------------------------------------
extern "C" void kernel_launch(void* const* d_in, const int* in_sizes, int n_in,
                              void* d_out, int out_size, void* d_ws, size_t ws_size,
                              hipStream_t stream) {
    const float* x = (const float*)d_in[0];
    const float* W = (const float*)d_in[1];
    const float* D = (const float*)d_in[2];
    float* out = (float*)d_out;
    float* ws  = (float*)d_ws;

    unsigned short* BmatT  = (unsigned short*)ws;               // 266240 bf16
    unsigned short* Xb     = (unsigned short*)(ws + 133120);    // 4259840 bf16
    unsigned short* Y2     = (unsigned short*)(ws + 2263040);   // 4259840 bf16
    unsigned short* fragB  = (unsigned short*)(ws + 4392960);   // 18432 bf16
    unsigned short* fragCi = fragB + 18432;                     // 20480 bf16

    k_prep  <<<16,   256, 0, stream>>>(W, fragB, fragCi, BmatT);
    k_fdft  <<<1024, 256, 0, stream>>>(x, D, (const bf16x8*)fragB, Xb);
    k_einsum<<<1040, 256, 0, stream>>>(Xb, BmatT, Y2);
    k_idft  <<<1024, 256, 0, stream>>>(Y2, (const bf16x8*)fragCi, out);
}

// Round 10
// 49.856 us; speedup vs baseline: 1.0308x; 1.0308x over previous
//
#include <hip/hip_runtime.h>
#include <hip/hip_bf16.h>

#define TWOPI_OVER_B 0.049087385212340517f  // 2*pi/128

typedef __attribute__((ext_vector_type(8))) short bf16x8;
typedef __attribute__((ext_vector_type(4))) float f32x4;

static __device__ __forceinline__ unsigned short f2bf(float f) {
    __hip_bfloat16 h = __float2bfloat16(f);
    return *reinterpret_cast<unsigned short*>(&h);
}
static __device__ __forceinline__ unsigned long long pack4(float a, float b, float c, float d) {
    return (unsigned long long)f2bf(a) | ((unsigned long long)f2bf(b) << 16)
         | ((unsigned long long)f2bf(c) << 32) | ((unsigned long long)f2bf(d) << 48);
}

// ---------------------------------------------------------------------------
// Prep (R8-validated, 16 blocks): each block builds local fB via sincos table,
// runs the W-spectrum MFMA DFT -> BmatT[k][o2][j2], and writes its 1/16
// stripe of global fragB (stage-A B-operand) and fragCi (stage-C B-operand).
__global__ __launch_bounds__(256) void k_prep(const float* __restrict__ W,
                                              unsigned short* __restrict__ fragB,
                                              unsigned short* __restrict__ fragCi,
                                              unsigned short* __restrict__ BmatT) {
    __shared__ char smem[73984];               // xs/Yl union
    __shared__ unsigned short fB[18432];
    __shared__ float tbl[256];
    int tid = threadIdx.x;
    int bw = blockIdx.x;                       // 0..15, 2 o's each
    unsigned long long* xs8 = (unsigned long long*)smem;
    float* Yl = (float*)smem;

    if (tid < 128) {
        float s, c;
        sincosf(TWOPI_OVER_B * (float)tid, &s, &c);
        tbl[tid] = c; tbl[128 + tid] = s;
    }
    __syncthreads();

    for (int i = tid; i < 18432; i += 256) {   // local fragB via table
        int e = i & 7, l2 = (i >> 3) & 63, kb = (i >> 9) & 3, c = i >> 11;
        int kr = c * 16 + (l2 & 15);
        int t  = kb * 32 + (l2 >> 4) * 8 + e;
        float v = 0.f;
        if (kr < 65)       v =  tbl[(kr * t) & 127];
        else if (kr < 130) v = -tbl[128 + (((kr - 65) * t) & 127)];
        fB[i] = f2bf(v);
    }
    // global fragB stripe (1152/block) + fragCi stripe (1280/block)
    for (int i = bw * 1152 + tid; i < (bw + 1) * 1152; i += 256) {
        int e = i & 7, l2 = (i >> 3) & 63, kb = (i >> 9) & 3, c = i >> 11;
        int kr = c * 16 + (l2 & 15);
        int t  = kb * 32 + (l2 >> 4) * 8 + e;
        float v = 0.f;
        if (kr < 65)       v =  tbl[(kr * t) & 127];
        else if (kr < 130) v = -tbl[128 + (((kr - 65) * t) & 127)];
        fragB[i] = f2bf(v);
    }
    for (int i = bw * 1280 + tid; i < (bw + 1) * 1280; i += 256) {
        int e = i & 7, l2 = (i >> 3) & 63;
        int ckb = i >> 9; int kb = ckb % 5, c = ckb / 5;
        int kr = kb * 32 + (l2 >> 4) * 8 + e;
        int t  = c * 16 + (l2 & 15);
        float v = 0.f;
        if (kr < 65)       v =  tbl[(kr * t) & 127];
        else if (kr < 130) v = -tbl[128 + (((kr - 65) * t) & 127)];
        fragCi[i] = f2bf(v);
    }
    #pragma unroll
    for (int it = 0; it < 8; ++it) {           // stage W: 64 rows x 128
        int f  = tid + it * 256;
        float4 wa = ((const float4*)W)[(size_t)bw * 2048 + f];
        int rl = f >> 5;
        int t0 = (f & 31) * 4;
        int byte = (rl * 256 + t0 * 2) ^ ((rl & 7) << 4);
        xs8[byte >> 3] = pack4(wa.x, wa.y, wa.z, wa.w);
    }
    __syncthreads();

    int l = tid & 63, w = tid >> 6;
    int rl_a = w * 16 + (l & 15);
    int coff = (l >> 4) * 16;
    bf16x8 a[4];
    #pragma unroll
    for (int kb = 0; kb < 4; ++kb) {
        int byte = (rl_a * 256 + kb * 64 + coff) ^ ((rl_a & 7) << 4);
        a[kb] = *(const bf16x8*)(smem + byte);
    }
    __syncthreads();                           // xs dead; Yl overwrites

    f32x4 acc[9];
    #pragma unroll
    for (int c = 0; c < 9; ++c) acc[c] = (f32x4)0.f;
    #pragma unroll
    for (int c = 0; c < 9; ++c)
        #pragma unroll
        for (int kb = 0; kb < 4; ++kb)
            acc[c] = __builtin_amdgcn_mfma_f32_16x16x32_bf16(a[kb], ((const bf16x8*)fB)[(c * 4 + kb) * 64 + l], acc[c], 0, 0, 0);

    int rowd = w * 16 + (l >> 4) * 4;
    int cold = l & 15;
    #pragma unroll
    for (int c = 0; c < 9; ++c)
        #pragma unroll
        for (int r = 0; r < 4; ++r)
            Yl[(rowd + r) * 145 + c * 16 + cold] = acc[c][r];
    __syncthreads();

    int o0 = bw * 2;
    for (int c2 = tid; c2 < 4160; c2 += 256) {
        int k = c2 >> 6, sub = c2 & 63;
        int oo = sub >> 5, h = (sub >> 4) & 1, t = sub & 15;
        int j0 = t * 4;
        float sc = (k == 0 || k == 64) ? (1.f / 128.f) : (2.f / 128.f);
        int col; float sgn;
        if (j0 < 32) { col = h ? 65 + k : k;  sgn = h ? -sc : sc; }
        else         { col = h ? k : 65 + k;  sgn = sc; }
        int rlb = oo * 32 + (j0 & 31);
        unsigned long long pk = pack4(sgn * Yl[(rlb + 0) * 145 + col], sgn * Yl[(rlb + 1) * 145 + col],
                                      sgn * Yl[(rlb + 2) * 145 + col], sgn * Yl[(rlb + 3) * 145 + col]);
        int o2 = h * 32 + o0 + oo;
        *(unsigned long long*)(BmatT + ((size_t)k * 64 + o2) * 64 + j0) = pk;
    }
}

// ---------------------------------------------------------------------------
// Stage A (R3 verbatim): X DFT with Yl f32 bounce -> coalesced Xb stores.
__global__ __launch_bounds__(256) void k_fdft(const float* __restrict__ x,
                                              const float* __restrict__ D,
                                              const bf16x8* __restrict__ fragB,
                                              unsigned short* __restrict__ Xb) {
    __shared__ char smem[37120];   // xs 16384 ∪ Yl 64*145*4
    unsigned long long* xs8 = (unsigned long long*)smem;
    float* Yl = (float*)smem;
    int tid = threadIdx.x;
    int n0 = blockIdx.x * 2;

    #pragma unroll
    for (int it = 0; it < 8; ++it) {       // 2048 float4 = 2 rows of x
        int f  = tid + it * 256;
        int nn = f >> 10;
        int f4 = f & 1023;
        float4 xa = ((const float4*)(x + (size_t)(n0 + nn) * 4096))[f4];
        float4 da = ((const float4*)D)[f4];
        int rl = nn * 32 + (f4 >> 5);
        int t0 = (f4 & 31) * 4;
        int byte = (rl * 256 + t0 * 2) ^ ((rl & 7) << 4);
        xs8[byte >> 3] = pack4(xa.x * da.x, xa.y * da.y, xa.z * da.z, xa.w * da.w);
    }
    __syncthreads();

    int l = tid & 63, w = tid >> 6;
    int rl_a = w * 16 + (l & 15);
    int coff = (l >> 4) * 16;
    bf16x8 a[4];
    #pragma unroll
    for (int kb = 0; kb < 4; ++kb) {
        int byte = (rl_a * 256 + kb * 64 + coff) ^ ((rl_a & 7) << 4);
        a[kb] = *(const bf16x8*)(smem + byte);
    }
    f32x4 acc[9];
    #pragma unroll
    for (int c = 0; c < 9; ++c) acc[c] = (f32x4)0.f;
    #pragma unroll
    for (int c = 0; c < 9; ++c)
        #pragma unroll
        for (int kb = 0; kb < 4; ++kb)
            acc[c] = __builtin_amdgcn_mfma_f32_16x16x32_bf16(a[kb], fragB[(c * 4 + kb) * 64 + l], acc[c], 0, 0, 0);
    __syncthreads();                        // xs dead; reuse as Yl

    int rowd = w * 16 + (l >> 4) * 4;
    int cold = l & 15;
    #pragma unroll
    for (int c = 0; c < 9; ++c)
        #pragma unroll
        for (int r = 0; r < 4; ++r)
            Yl[(rowd + r) * 145 + c * 16 + cold] = acc[c][r];
    __syncthreads();

    for (int c2 = tid; c2 < 2080; c2 += 256) {
        int k = c2 >> 5, sub = c2 & 31, nn = sub >> 4, t = sub & 15;
        int j0 = t * 4;
        int col = (j0 < 32) ? k : 65 + k;
        int rlb = nn * 32 + (j0 & 31);
        unsigned long long pk = pack4(Yl[(rlb + 0) * 145 + col], Yl[(rlb + 1) * 145 + col],
                                      Yl[(rlb + 2) * 145 + col], Yl[(rlb + 3) * 145 + col]);
        *(unsigned long long*)(Xb + ((size_t)k * 1024 + n0 + nn) * 64 + j0) = pk;
    }
}

// ---------------------------------------------------------------------------
// Stage B (R3 verbatim): per-k GEMM [1024x64]x[64x64] -> Y2[k][n][o2].
__global__ __launch_bounds__(256) void k_einsum(const unsigned short* __restrict__ Xb,
                                                const unsigned short* __restrict__ BmatT,
                                                unsigned short* __restrict__ Y2) {
    __shared__ char lds[16384];
    int tid = threadIdx.x, l = tid & 63, w = tid >> 6;
    int k = blockIdx.x >> 3, mt = blockIdx.x & 7;
    int m0 = mt * 128 + w * 32;
    int lr = l & 15, lq = l >> 4;

    bf16x8 a[2][2], b[4][2];
    #pragma unroll
    for (int rf = 0; rf < 2; ++rf)
        #pragma unroll
        for (int kb = 0; kb < 2; ++kb)
            a[rf][kb] = *(const bf16x8*)(Xb + ((size_t)k * 1024 + m0 + rf * 16 + lr) * 64 + kb * 32 + lq * 8);
    #pragma unroll
    for (int cf = 0; cf < 4; ++cf)
        #pragma unroll
        for (int kb = 0; kb < 2; ++kb)
            b[cf][kb] = *(const bf16x8*)(BmatT + ((size_t)k * 64 + cf * 16 + lr) * 64 + kb * 32 + lq * 8);

    f32x4 acc[2][4];
    #pragma unroll
    for (int rf = 0; rf < 2; ++rf)
        #pragma unroll
        for (int cf = 0; cf < 4; ++cf) acc[rf][cf] = (f32x4)0.f;
    #pragma unroll
    for (int rf = 0; rf < 2; ++rf)
        #pragma unroll
        for (int cf = 0; cf < 4; ++cf) {
            acc[rf][cf] = __builtin_amdgcn_mfma_f32_16x16x32_bf16(a[rf][0], b[cf][0], acc[rf][cf], 0, 0, 0);
            acc[rf][cf] = __builtin_amdgcn_mfma_f32_16x16x32_bf16(a[rf][1], b[cf][1], acc[rf][cf], 0, 0, 0);
        }

    #pragma unroll
    for (int rf = 0; rf < 2; ++rf)
        #pragma unroll
        for (int cf = 0; cf < 4; ++cf)
            #pragma unroll
            for (int rr = 0; rr < 4; ++rr) {
                int row = rf * 16 + lq * 4 + rr;
                int col = cf * 16 + lr;
                int byte = w * 4096 + ((row * 128 + col * 2) ^ ((row & 7) << 4));
                *(unsigned short*)(lds + byte) = f2bf(acc[rf][cf][rr]);
            }
    __syncthreads();
    #pragma unroll
    for (int i = 0; i < 4; ++i) {
        int row = i * 8 + (l >> 3);
        int byte = w * 4096 + ((row * 128 + (l & 7) * 16) ^ ((row & 7) << 4));
        bf16x8 v = *(const bf16x8*)(lds + byte);
        *(bf16x8*)(Y2 + ((size_t)k * 1024 + m0 + row) * 64 + (l & 7) * 8) = v;
    }
}

// ---------------------------------------------------------------------------
// Stage C (R3 verbatim): iDFT, rows=(n,o), K=160 pad.
__global__ __launch_bounds__(256) void k_idft(const unsigned short* __restrict__ Y2,
                                              const bf16x8* __restrict__ fragCi,
                                              float* __restrict__ out) {
    __shared__ char smem[20480];            // ys[64][160] bf16, swizzled
    int tid = threadIdx.x;
    int row0 = blockIdx.x * 64;
    int n0 = blockIdx.x * 2;

    for (int i = tid; i < 1920; i += 256) {
        int rl = i / 30, cp = 130 + i % 30;
        int byte = (rl * 320 + cp * 2) ^ ((rl & 7) << 4);
        *(unsigned short*)(smem + byte) = 0;
    }
    for (int c2 = tid; c2 < 2080; c2 += 256) {
        int k = c2 >> 5, sub = c2 & 31, nn = sub >> 4, t = sub & 15;
        unsigned long long v = *(const unsigned long long*)(Y2 + ((size_t)k * 1024 + n0 + nn) * 64 + t * 4);
        int o2_0 = t * 4;
        int col = (o2_0 < 32) ? k : 65 + k;
        int r0 = nn * 32 + (o2_0 & 31);
        #pragma unroll
        for (int i = 0; i < 4; ++i) {
            int rl = r0 + i;
            int byte = (rl * 320 + col * 2) ^ ((rl & 7) << 4);
            *(unsigned short*)(smem + byte) = (unsigned short)(v >> (16 * i));
        }
    }
    __syncthreads();

    int l = tid & 63, w = tid >> 6;
    int rl_a = w * 16 + (l & 15);
    int coff = (l >> 4) * 16;
    bf16x8 a[5];
    #pragma unroll
    for (int kb = 0; kb < 5; ++kb) {
        int byte = (rl_a * 320 + kb * 64 + coff) ^ ((rl_a & 7) << 4);
        a[kb] = *(const bf16x8*)(smem + byte);
    }
    f32x4 acc[8];
    #pragma unroll
    for (int c = 0; c < 8; ++c) acc[c] = (f32x4)0.f;
    #pragma unroll
    for (int c = 0; c < 8; ++c)
        #pragma unroll
        for (int kb = 0; kb < 5; ++kb)
            acc[c] = __builtin_amdgcn_mfma_f32_16x16x32_bf16(a[kb], fragCi[(c * 5 + kb) * 64 + l], acc[c], 0, 0, 0);

    int rowd = row0 + w * 16 + (l >> 4) * 4;
    int cold = l & 15;
    #pragma unroll
    for (int c = 0; c < 8; ++c)
        #pragma unroll
        for (int r = 0; r < 4; ++r)
            out[(size_t)(rowd + r) * 128 + c * 16 + cold] = acc[c][r];
}

// ---------------------------------------------------------------------------
extern "C" void kernel_launch(void* const* d_in, const int* in_sizes, int n_in,
                              void* d_out, int out_size, void* d_ws, size_t ws_size,
                              hipStream_t stream) {
    const float* x = (const float*)d_in[0];
    const float* W = (const float*)d_in[1];
    const float* D = (const float*)d_in[2];
    float* out = (float*)d_out;
    float* ws  = (float*)d_ws;

    unsigned short* BmatT  = (unsigned short*)ws;               // 266240 bf16
    unsigned short* Xb     = (unsigned short*)(ws + 133120);    // 4259840 bf16
    unsigned short* Y2     = (unsigned short*)(ws + 2263040);   // 4259840 bf16
    unsigned short* fragB  = (unsigned short*)(ws + 4392960);   // 18432 bf16
    unsigned short* fragCi = fragB + 18432;                     // 20480 bf16

    k_prep  <<<16,  256, 0, stream>>>(W, fragB, fragCi, BmatT);
    k_fdft  <<<512, 256, 0, stream>>>(x, D, (const bf16x8*)fragB, Xb);
    k_einsum<<<520, 256, 0, stream>>>(Xb, BmatT, Y2);
    k_idft  <<<512, 256, 0, stream>>>(Y2, (const bf16x8*)fragCi, out);
}